// Round 2
// baseline (25167.137 us; speedup 1.0000x reference)
//
#include <hip/hip_runtime.h>
#include <hip/hip_fp16.h>

#define N 4096
#define L 4096
#define NPART 16   // i-chunks (rows 256 each)
#define NJB 32     // j-blocks (cols 128 each)
#define CPB 128    // cols per block
#define RPB 256    // rows per block

#define NN ((size_t)N * (size_t)N)
#define SLOT ((size_t)N * 4)

#define AS(p, v) __hip_atomic_store((p), (v), __ATOMIC_RELAXED, __HIP_MEMORY_SCOPE_AGENT)
#define AL(p)    __hip_atomic_load((p), __ATOMIC_RELAXED, __HIP_MEMORY_SCOPE_AGENT)

typedef _Float16 f16x8 __attribute__((ext_vector_type(8)));
typedef float f32x4 __attribute__((ext_vector_type(4)));

// ---------- init: zero d_out, seed triple partial buffer, zero ready counters ----------
__global__ __launch_bounds__(256) void init_kernel(const float* __restrict__ sd,
                                                   float* __restrict__ vwpart,
                                                   unsigned* __restrict__ ready,
                                                   float* __restrict__ out) {
    int g = blockIdx.x * 256 + threadIdx.x;          // grid 1536 -> 393216 threads
    if (g < L * 4) out[g] = 0.0f;
    if (g < 3 * NPART * N) AS(&vwpart[g], (g < N) ? sd[g] : 0.0f);  // buf0 part0 = sd
    if (g < NPART * 64) AS(&ready[g], 0u);
}

// ---------- descriptor build: robust int32/int64 decode; mode 0/1/2 = direct/pair/quad ----------
__global__ __launch_bounds__(256) void build_desc_kernel(const int* __restrict__ seq32,
                                                         unsigned char* __restrict__ midx,
                                                         int mode) {
    __shared__ int any_odd;
    if (threadIdx.x == 0) any_odd = 0;
    __syncthreads();
    int acc = 0;
    for (int i = threadIdx.x; i < L / 2; i += 256) acc |= seq32[2 * i + 1];
    if (acc) any_odd = 1;
    __syncthreads();
    const int is64 = (any_odd == 0);
#define SYM(t) ((is64 ? seq32[2 * (t)] : seq32[(t)]) & 1)
    if (mode == 2) {
        for (int k = threadIdx.x; k < L / 4; k += 256)
            midx[k] = (unsigned char)(SYM(4 * k) * 8 + SYM(4 * k + 1) * 4 +
                                      SYM(4 * k + 2) * 2 + SYM(4 * k + 3));
    } else if (mode == 1) {
        for (int k = threadIdx.x; k < L / 2; k += 256)
            midx[k] = (unsigned char)(SYM(2 * k) * 2 + SYM(2 * k + 1));
    } else {
        for (int t = threadIdx.x; t < L; t += 256)
            midx[t] = (unsigned char)SYM(t);
    }
#undef SYM
}

// ---------- softmax over T rows -> fp16 Tm[s][i][j] + row-mass correction ----------
__global__ __launch_bounds__(256) void softmax_T_kernel(const float* __restrict__ T,
                                                        unsigned short* __restrict__ Tm,
                                                        float* __restrict__ rowc) {
    int row = blockIdx.x;              // 0..8191 == i*2 + s
    int i = row >> 1, s = row & 1;
    const float* src = T + (size_t)row * N;
    unsigned short* dst = Tm + ((size_t)s << 24) + ((size_t)i << 12);
    int tid = threadIdx.x;

    float vals[16];
    float mx = -1e30f;
#pragma unroll
    for (int k = 0; k < 16; k++) {
        vals[k] = src[tid + (k << 8)];
        mx = fmaxf(mx, vals[k]);
    }
#pragma unroll
    for (int o = 32; o > 0; o >>= 1) mx = fmaxf(mx, __shfl_xor(mx, o));
    __shared__ float red[4];
    int wid = tid >> 6;
    if ((tid & 63) == 0) red[wid] = mx;
    __syncthreads();
    mx = fmaxf(fmaxf(red[0], red[1]), fmaxf(red[2], red[3]));
    __syncthreads();

    float sum = 0.0f;
#pragma unroll
    for (int k = 0; k < 16; k++) {
        vals[k] = __expf(vals[k] - mx);
        sum += vals[k];
    }
#pragma unroll
    for (int o = 32; o > 0; o >>= 1) sum += __shfl_xor(sum, o);
    if ((tid & 63) == 0) red[wid] = sum;
    __syncthreads();
    sum = red[0] + red[1] + red[2] + red[3];
    __syncthreads();
    float inv = 1.0f / sum;

    float qs = 0.0f;
#pragma unroll
    for (int k = 0; k < 16; k++) {
        __half h = __float2half_rn(vals[k] * inv);
        dst[tid + (k << 8)] = __half_as_ushort(h);
        qs += __half2float(h);
    }
#pragma unroll
    for (int o = 32; o > 0; o >>= 1) qs += __shfl_xor(qs, o);
    if ((tid & 63) == 0) red[wid] = qs;
    __syncthreads();
    if (tid == 0) {
        float q = red[0] + red[1] + red[2] + red[3];
        rowc[(size_t)s * N + i] = 1.0f / q;
    }
}

// ---------- softmax over O rows (4 wide) -> fp32 OW slots 0,1 ----------
__global__ __launch_bounds__(256) void softmax_O_kernel(const float* __restrict__ O,
                                                        float* __restrict__ OW) {
    int r = blockIdx.x * 256 + threadIdx.x;        // 0..8191 == i*2 + s
    if (r < 2 * N) {
        float4 x = *(const float4*)(O + (size_t)r * 4);
        float mx = fmaxf(fmaxf(x.x, x.y), fmaxf(x.z, x.w));
        float e0 = __expf(x.x - mx), e1 = __expf(x.y - mx);
        float e2 = __expf(x.z - mx), e3 = __expf(x.w - mx);
        float inv = 1.0f / (e0 + e1 + e2 + e3);
        int i = r >> 1, s = r & 1;
        *(float4*)(OW + (size_t)s * SLOT + (size_t)i * 4) =
            make_float4(e0 * inv, e1 * inv, e2 * inv, e3 * inv);
    }
}

// ---------- MFMA GEMM: C[pair] = A[pair>>ash] x B[pair&bmask], fp16 in/out ----------
// (validated in R10) grid = npairs*1024 blocks; 128x128 C-tile; 4 waves x 64x64.
__global__ __launch_bounds__(256) void gemm_kernel(const unsigned short* __restrict__ Abase,
                                                   const unsigned short* __restrict__ Bbase,
                                                   unsigned short* __restrict__ Cbase,
                                                   int ash, int bmask) {
    int bid = blockIdx.x;
    int pair = bid >> 10;
    int tile = bid & 1023;
    int i0 = (tile >> 5) << 7;
    int j0 = (tile & 31) << 7;
    const unsigned short* A = Abase + (size_t)(pair >> ash) * NN;
    const unsigned short* B = Bbase + (size_t)(pair & bmask) * NN;
    unsigned short* Pm = Cbase + (size_t)pair * NN;

    __shared__ _Float16 Asd[128][40];
    __shared__ unsigned int Btw[128][20];

    const int tid = threadIdx.x;
    const int w = tid >> 6, ln = tid & 63;
    const int wrow = (w >> 1) << 6, wcol = (w & 1) << 6;
    const int q = ln >> 4, l15 = ln & 15;

    const int ar = tid >> 1, ah = tid & 1;
    const int bk2 = tid & 15, bng = tid >> 4;

    f32x4 acc[4][4] = {};

    for (int k0 = 0; k0 < N; k0 += 32) {
        const uint4* ga = (const uint4*)(A + (size_t)(i0 + ar) * N + k0 + ah * 16);
        uint4 a0 = ga[0], a1 = ga[1];
        *(uint4*)&Asd[ar][ah * 16] = a0;
        *(uint4*)&Asd[ar][ah * 16 + 8] = a1;
        const unsigned short* gb0 = B + (size_t)(k0 + 2 * bk2) * N + j0 + bng * 8;
        uint4 b0 = *(const uint4*)gb0;
        uint4 b1 = *(const uint4*)(gb0 + N);
        const unsigned short* e0 = (const unsigned short*)&b0;
        const unsigned short* e1 = (const unsigned short*)&b1;
#pragma unroll
        for (int jj = 0; jj < 8; jj++)
            Btw[bng * 8 + jj][bk2] = (unsigned)e0[jj] | ((unsigned)e1[jj] << 16);
        __syncthreads();

        f16x8 af[4], bf[4];
#pragma unroll
        for (int ti = 0; ti < 4; ti++)
            af[ti] = *(const f16x8*)&Asd[wrow + ti * 16 + l15][q * 8];
#pragma unroll
        for (int tj = 0; tj < 4; tj++)
            bf[tj] = *(const f16x8*)&Btw[wcol + tj * 16 + l15][q * 4];
#pragma unroll
        for (int ti = 0; ti < 4; ti++)
#pragma unroll
            for (int tj = 0; tj < 4; tj++)
                acc[ti][tj] = __builtin_amdgcn_mfma_f32_16x16x32_f16(
                    af[ti], bf[tj], acc[ti][tj], 0, 0, 0);
        __syncthreads();
    }

#pragma unroll
    for (int ti = 0; ti < 4; ti++)
#pragma unroll
        for (int tj = 0; tj < 4; tj++)
#pragma unroll
            for (int reg = 0; reg < 4; reg++) {
                int row = i0 + wrow + ti * 16 + q * 4 + reg;
                int col = j0 + wcol + tj * 16 + l15;
                Pm[(size_t)row * N + col] =
                    __half_as_ushort(__float2half_rn(acc[ti][tj][reg]));
            }
}

// ---------- row sums of fp16 matrices -> rc = 1/sum (exact stochasticity) ----------
__global__ __launch_bounds__(256) void rowsum_kernel(const unsigned short* __restrict__ P,
                                                     float* __restrict__ rc) {
    int b = blockIdx.x;                        // mat*4096 + row
    const unsigned short* row = P + (size_t)b * N;
    int tid = threadIdx.x;
    const uint4* rp = (const uint4*)row + tid * 2;
    uint4 w0 = rp[0], w1 = rp[1];
    const __half* h0 = (const __half*)&w0;
    const __half* h1 = (const __half*)&w1;
    float s = 0.0f;
#pragma unroll
    for (int j = 0; j < 8; j++) s += __half2float(h0[j]) + __half2float(h1[j]);
#pragma unroll
    for (int o = 32; o > 0; o >>= 1) s += __shfl_xor(s, o);
    __shared__ float red[4];
    if ((tid & 63) == 0) red[tid >> 6] = s;
    __syncthreads();
    if (tid == 0) rc[b] = 1.0f / (red[0] + red[1] + red[2] + red[3]);
}

// ---------- generic N x 4 projection: dst[i][c] = rc[i] * sum_j M[i][j]*Q[j][c] ----------
// phase 1: slots s<4 -> W1[ab]=corr(Tm_a)*Om_b (dst 2+s); s in 4..11 -> W2[abc]
//   = corr(P_ab)*Om_c (dst 6+q). phase 2: q<16 -> W3[abcd]=corr(P_ab)*W1[cd] (dst 14+q).
__global__ __launch_bounds__(256) void proj_kernel(const unsigned short* __restrict__ Tm,
                                                   const unsigned short* __restrict__ P,
                                                   const float* __restrict__ rowc,
                                                   const float* __restrict__ rowc2,
                                                   float* __restrict__ OW, int phase) {
    int bid = blockIdx.x;
    int s = bid >> 12, i = bid & 4095;
    const unsigned short* M; const float* rc; const float* Q; float* dst;
    if (phase == 1) {
        if (s < 4) { M = Tm + (size_t)(s >> 1) * NN; rc = rowc + (size_t)(s >> 1) * N;
                     Q = OW + (size_t)(s & 1) * SLOT; dst = OW + (size_t)(2 + s) * SLOT; }
        else { int q = s - 4; M = P + (size_t)(q >> 1) * NN; rc = rowc2 + (size_t)(q >> 1) * N;
               Q = OW + (size_t)(q & 1) * SLOT; dst = OW + (size_t)(6 + q) * SLOT; }
    } else {
        int q = s; M = P + (size_t)(q >> 2) * NN; rc = rowc2 + (size_t)(q >> 2) * N;
        Q = OW + (size_t)(2 + (q & 3)) * SLOT; dst = OW + (size_t)(14 + q) * SLOT;
    }
    const unsigned short* row = M + (size_t)i * N;
    int tid = threadIdx.x;
    const uint4* rp = (const uint4*)row + tid * 2;
    uint4 w0 = rp[0], w1 = rp[1];
    const __half* h0 = (const __half*)&w0;
    const __half* h1 = (const __half*)&w1;
    int j0 = tid * 16;
    float ac[4] = {};
#pragma unroll
    for (int j = 0; j < 8; j++) {
        float tv = __half2float(h0[j]);
        float4 o = *(const float4*)(Q + (size_t)(j0 + j) * 4);
        ac[0] += tv * o.x; ac[1] += tv * o.y; ac[2] += tv * o.z; ac[3] += tv * o.w;
        float tv1 = __half2float(h1[j]);
        float4 o1 = *(const float4*)(Q + (size_t)(j0 + 8 + j) * 4);
        ac[0] += tv1 * o1.x; ac[1] += tv1 * o1.y; ac[2] += tv1 * o1.z; ac[3] += tv1 * o1.w;
    }
#pragma unroll
    for (int e = 0; e < 4; e++)
#pragma unroll
        for (int o = 32; o > 0; o >>= 1) ac[e] += __shfl_xor(ac[e], o);
    __shared__ float red[4][4];
    if ((tid & 63) == 0)
#pragma unroll
        for (int e = 0; e < 4; e++) red[tid >> 6][e] = ac[e];
    __syncthreads();
    if (tid < 4)
        dst[(size_t)i * 4 + tid] =
            (red[0][tid] + red[1][tid] + red[2][tid] + red[3][tid]) * rc[i];
}

// ---------- persistent scan (regular launch, p2p sync; NPART=16 tiling) ----------
// 512 blocks: jb = bid&31 (128 cols), ic = bid>>5 (256 rows).
// wait ready[ic] >= 32k (32 producers: jb_p in {2ic,2ic+1} x 16 ic_p);
// bump ready[jb>>1]. Triple-buffered partials (two-level transitivity => safe).
// Block jb<OPS computes output projection jb via OW slot (m,jb)-indexed.
//
// R11 change: register-prefetch of the NEXT step's 64 KiB matrix tile
// (16 x uint4 per thread). midx[k+1] is input-independent, so the matrix
// load — the only large-latency item on the serial dependency chain —
// is issued right after this step's publish drain and flies concurrently
// with bump/poll/partial-read. The post-poll barrier is a RAW s_barrier
// (control-only handoff; __syncthreads' implicit vmcnt(0) drain there
// would kill the in-flight prefetch). All barriers guarding LDS/global
// handoffs remain __syncthreads().
__global__ __launch_bounds__(256, 2) void scan_kernel(const unsigned short* __restrict__ Mbase,
                                                      const float* __restrict__ rc,
                                                      const float* __restrict__ OW,
                                                      const unsigned char* __restrict__ midx,
                                                      float* __restrict__ vwpart,
                                                      unsigned* __restrict__ ready,
                                                      float* __restrict__ out,
                                                      int S, int OPS) {
    const int tid = threadIdx.x;
    const int jb = blockIdx.x & 31;
    const int ic = blockIdx.x >> 5;      // 0..15
    const int i0 = ic * RPB;
    const int j0 = jb * CPB;

    __shared__ float v[RPB];      // raw state rows
    __shared__ float vc[RPB];     // row-mass-corrected state rows
    __shared__ float colacc[CPB];
    __shared__ float oacc[4];

    const int cg = tid & 15;             // col group: 8 cols each
    const int rg = tid >> 4;             // row group: 16 groups x 16 rows

    unsigned* wait_ctr = &ready[ic * 64];
    unsigned* bump_ctr = &ready[(jb >> 1) * 64];

    // thread-constant byte-tile offset within any matrix
    const size_t tileoff = (size_t)(i0 + rg * 16) * N + (size_t)(j0 + cg * 8);

    // prefetch buffer: this thread's whole 256 B tile slice (64 VGPRs)
    uint4 mreg[16];
    int mcur = (int)midx[0];
    {
        const unsigned short* b = Mbase + (size_t)mcur * NN + tileoff;
#pragma unroll
        for (int r = 0; r < 16; r++) mreg[r] = *(const uint4*)(b + (size_t)r * N);
    }

    for (int k = 0; k < S; k++) {
        const int m = mcur;
        const int mnext = (k + 1 < S) ? (int)midx[k + 1] : 0;
        const float* rcrow = rc + (size_t)m * N;
        const float* vin  = vwpart + (size_t)(k % 3) * (NPART * N);
        float*       vout = vwpart + (size_t)((k + 1) % 3) * (NPART * N);

        // ---- wait for this step's input partials (monotone counter) ----
        if (tid == 0) {
            unsigned target = 32u * (unsigned)k;
            while (AL(wait_ctr) < target) __builtin_amdgcn_s_sleep(1);
        }
        // RAW barrier: control-only sync. Producers' stores are already at
        // MALL (they drained before bumping), and our partial reads below
        // are agent-scope atomic loads, so no waitcnt drain is needed here.
        asm volatile("" ::: "memory");
        __builtin_amdgcn_s_barrier();
        asm volatile("" ::: "memory");

        // ---- stage v rows: all 256 threads sum 16 partials for one row ----
        // (the ds_write data-dependency drains vmcnt, i.e. also waits the
        //  matrix prefetch — which compute needs immediately after anyway)
        {
            float accv = 0.0f;
#pragma unroll
            for (int p = 0; p < NPART; p++) accv += AL(&vin[p * N + i0 + tid]);
            v[tid] = accv;
            vc[tid] = accv * rcrow[i0 + tid];
        }
        if (tid < CPB) colacc[tid] = 0.0f;
        if (tid < 4) oacc[tid] = 0.0f;
        __syncthreads();

        // ---- partial matvec from prefetched regs: rows [i0+rg*16,+16), cols [j0+cg*8,+8) ----
        float a[8];
#pragma unroll
        for (int e = 0; e < 8; e++) a[e] = 0.0f;
#pragma unroll
        for (int r = 0; r < 16; r++) {
            uint4 w = mreg[r];
            float vi = vc[rg * 16 + r];
            float2 f0 = __half22float2(*(__half2*)&w.x);
            float2 f1 = __half22float2(*(__half2*)&w.y);
            float2 f2 = __half22float2(*(__half2*)&w.z);
            float2 f3 = __half22float2(*(__half2*)&w.w);
            a[0] += vi * f0.x; a[1] += vi * f0.y;
            a[2] += vi * f1.x; a[3] += vi * f1.y;
            a[4] += vi * f2.x; a[5] += vi * f2.y;
            a[6] += vi * f3.x; a[7] += vi * f3.y;
        }
#pragma unroll
        for (int e = 0; e < 8; e++) atomicAdd(&colacc[cg * 8 + e], a[e]);

        // ---- output projection jb (blocks jb < OPS) — RAW state v ----
        if (jb < OPS) {
            int slot;
            if (OPS == 4) slot = (jb == 0) ? (m >> 3) : (jb == 1) ? 2 + (m >> 2)
                               : (jb == 2) ? 6 + (m >> 1) : 14 + m;
            else if (OPS == 2) slot = (jb == 0) ? (m >> 1) : 2 + m;
            else slot = m;
            const float* pr = OW + (size_t)slot * SLOT;
            int r = tid >> 2, c = tid & 3;   // r in [0,64)
            float p = v[r]       * pr[(size_t)(i0 + r) * 4 + c]
                    + v[r + 64]  * pr[(size_t)(i0 + r + 64) * 4 + c]
                    + v[r + 128] * pr[(size_t)(i0 + r + 128) * 4 + c]
                    + v[r + 192] * pr[(size_t)(i0 + r + 192) * 4 + c];
            p += __shfl_down(p, 32); p += __shfl_down(p, 16);
            p += __shfl_down(p, 8);  p += __shfl_down(p, 4);
            if ((tid & 63) < 4) atomicAdd(&oacc[c], p);
        }
        __syncthreads();

        // ---- publish this block's exclusive partial slice (agent-scope) ----
        if (tid < CPB) AS(&vout[(size_t)ic * N + j0 + tid], colacc[tid]);
        if (jb < OPS && tid < 4) atomicAdd(&out[(k * OPS + jb) * 4 + tid], oacc[tid]);
        __syncthreads();   // drains vmcnt(0) -> slice visible at MALL
                           // (prefetch not yet issued, so this drain is cheap)

        // ---- issue next step's matrix tile loads; they overlap bump+poll+stage ----
        if (k + 1 < S) {
            const unsigned short* b = Mbase + (size_t)mnext * NN + tileoff;
#pragma unroll
            for (int r = 0; r < 16; r++) mreg[r] = *(const uint4*)(b + (size_t)r * N);
        }

        if (tid == 0) {
            __hip_atomic_fetch_add(bump_ctr, 1u, __ATOMIC_RELAXED,
                                   __HIP_MEMORY_SCOPE_AGENT);
        }
        mcur = mnext;
    }
}

extern "C" void kernel_launch(void* const* d_in, const int* in_sizes, int n_in,
                              void* d_out, int out_size, void* d_ws, size_t ws_size,
                              hipStream_t stream) {
    const float* sd  = (const float*)d_in[0];   // [4096]
    const int*   seq = (const int*)d_in[1];     // [4096]
    const float* T   = (const float*)d_in[2];   // [4096,2,4096]
    const float* O   = (const float*)d_in[3];   // [4096,2,4]
    float* out = (float*)d_out;                 // [4096,4]

    const size_t TM_SZ = 2 * NN * 2;            // 64 MiB
    const size_t P_SZ  = 4 * NN * 2;            // 128 MiB
    const size_t P4_SZ = 16 * NN * 2;           // 512 MiB
    const size_t AUX_SZ = 0x400000;             // 4 MiB aux block

    int mode = (ws_size >= TM_SZ + P_SZ + P4_SZ + AUX_SZ) ? 2
             : (ws_size >= TM_SZ + P_SZ + AUX_SZ) ? 1 : 0;

    char* ws = (char*)d_ws;
    unsigned short* Tm = (unsigned short*)ws;
    unsigned short* P  = (unsigned short*)(ws + TM_SZ);
    unsigned short* P4 = (unsigned short*)(ws + TM_SZ + P_SZ);
    char* aux = ws + (mode == 2 ? TM_SZ + P_SZ + P4_SZ
                    : mode == 1 ? TM_SZ + P_SZ : TM_SZ);
    float* rowc   = (float*)(aux);               // 32 KB
    float* rowc2  = (float*)(aux + 0x8000);      // 64 KB
    float* rowc4  = (float*)(aux + 0x18000);     // 256 KB
    float* OW     = (float*)(aux + 0x58000);     // 32 slots x 64 KB = 2 MB
    float* vwpart = (float*)(aux + 0x258000);    // 768 KB
    unsigned* ready = (unsigned*)(aux + 0x318000);
    unsigned char* midx = (unsigned char*)(aux + 0x319000);

    hipLaunchKernelGGL(init_kernel, dim3(1536), dim3(256), 0, stream, sd, vwpart, ready, out);
    hipLaunchKernelGGL(build_desc_kernel, dim3(1), dim3(256), 0, stream, seq, midx, mode);
    hipLaunchKernelGGL(softmax_T_kernel, dim3(2 * N), dim3(256), 0, stream, T, Tm, rowc);
    hipLaunchKernelGGL(softmax_O_kernel, dim3(32), dim3(256), 0, stream, O, OW);

    if (mode == 2) {
        hipLaunchKernelGGL(gemm_kernel, dim3(4 * 1024), dim3(256), 0, stream, Tm, Tm, P, 1, 1);
        hipLaunchKernelGGL(rowsum_kernel, dim3(4 * N), dim3(256), 0, stream, P, rowc2);
        hipLaunchKernelGGL(gemm_kernel, dim3(16 * 1024), dim3(256), 0, stream, P, P, P4, 2, 3);
        hipLaunchKernelGGL(rowsum_kernel, dim3(16 * N), dim3(256), 0, stream, P4, rowc4);
        hipLaunchKernelGGL(proj_kernel, dim3(12 * N), dim3(256), 0, stream, Tm, P, rowc, rowc2, OW, 1);
        hipLaunchKernelGGL(proj_kernel, dim3(16 * N), dim3(256), 0, stream, Tm, P, rowc, rowc2, OW, 2);
        hipLaunchKernelGGL(scan_kernel, dim3(512), dim3(256), 0, stream,
                           P4, rowc4, OW, midx, vwpart, ready, out, L / 4, 4);
    } else if (mode == 1) {
        hipLaunchKernelGGL(gemm_kernel, dim3(4 * 1024), dim3(256), 0, stream, Tm, Tm, P, 1, 1);
        hipLaunchKernelGGL(rowsum_kernel, dim3(4 * N), dim3(256), 0, stream, P, rowc2);
        hipLaunchKernelGGL(proj_kernel, dim3(4 * N), dim3(256), 0, stream, Tm, P, rowc, rowc2, OW, 1);
        hipLaunchKernelGGL(scan_kernel, dim3(512), dim3(256), 0, stream,
                           P, rowc2, OW, midx, vwpart, ready, out, L / 2, 2);
    } else {
        hipLaunchKernelGGL(scan_kernel, dim3(512), dim3(256), 0, stream,
                           Tm, rowc, OW, midx, vwpart, ready, out, L, 1);
    }
}

// Round 3
// 22550.092 us; speedup vs baseline: 1.1161x; 1.1161x over previous
//
#include <hip/hip_runtime.h>
#include <hip/hip_fp16.h>

#define N 4096
#define L 4096
#define NPART 16   // i-chunks (rows 256 each)
#define NJB 32     // j-blocks (cols 128 each)
#define CPB 128    // cols per block
#define RPB 256    // rows per block

#define NN ((size_t)N * (size_t)N)
#define SLOT ((size_t)N * 4)

#define AS(p, v) __hip_atomic_store((p), (v), __ATOMIC_RELAXED, __HIP_MEMORY_SCOPE_AGENT)
#define AL(p)    __hip_atomic_load((p), __ATOMIC_RELAXED, __HIP_MEMORY_SCOPE_AGENT)

typedef _Float16 f16x8 __attribute__((ext_vector_type(8)));
typedef float f32x4 __attribute__((ext_vector_type(4)));

// ---------- init: zero d_out, seed triple partial buffer, zero ready counters ----------
__global__ __launch_bounds__(256) void init_kernel(const float* __restrict__ sd,
                                                   float* __restrict__ vwpart,
                                                   unsigned* __restrict__ ready,
                                                   float* __restrict__ out) {
    int g = blockIdx.x * 256 + threadIdx.x;          // grid 1536 -> 393216 threads
    if (g < L * 4) out[g] = 0.0f;
    if (g < 3 * NPART * N) AS(&vwpart[g], (g < N) ? sd[g] : 0.0f);  // buf0 part0 = sd
    if (g < NPART * 64) AS(&ready[g], 0u);
}

// ---------- descriptor build: robust int32/int64 decode; mode 0/1/2 = direct/pair/quad ----------
__global__ __launch_bounds__(256) void build_desc_kernel(const int* __restrict__ seq32,
                                                         unsigned char* __restrict__ midx,
                                                         int mode) {
    __shared__ int any_odd;
    if (threadIdx.x == 0) any_odd = 0;
    __syncthreads();
    int acc = 0;
    for (int i = threadIdx.x; i < L / 2; i += 256) acc |= seq32[2 * i + 1];
    if (acc) any_odd = 1;
    __syncthreads();
    const int is64 = (any_odd == 0);
#define SYM(t) ((is64 ? seq32[2 * (t)] : seq32[(t)]) & 1)
    if (mode == 2) {
        for (int k = threadIdx.x; k < L / 4; k += 256)
            midx[k] = (unsigned char)(SYM(4 * k) * 8 + SYM(4 * k + 1) * 4 +
                                      SYM(4 * k + 2) * 2 + SYM(4 * k + 3));
    } else if (mode == 1) {
        for (int k = threadIdx.x; k < L / 2; k += 256)
            midx[k] = (unsigned char)(SYM(2 * k) * 2 + SYM(2 * k + 1));
    } else {
        for (int t = threadIdx.x; t < L; t += 256)
            midx[t] = (unsigned char)SYM(t);
    }
#undef SYM
}

// ---------- softmax over T rows -> fp16 Tm[s][i][j] + row-mass correction ----------
__global__ __launch_bounds__(256) void softmax_T_kernel(const float* __restrict__ T,
                                                        unsigned short* __restrict__ Tm,
                                                        float* __restrict__ rowc) {
    int row = blockIdx.x;              // 0..8191 == i*2 + s
    int i = row >> 1, s = row & 1;
    const float* src = T + (size_t)row * N;
    unsigned short* dst = Tm + ((size_t)s << 24) + ((size_t)i << 12);
    int tid = threadIdx.x;

    float vals[16];
    float mx = -1e30f;
#pragma unroll
    for (int k = 0; k < 16; k++) {
        vals[k] = src[tid + (k << 8)];
        mx = fmaxf(mx, vals[k]);
    }
#pragma unroll
    for (int o = 32; o > 0; o >>= 1) mx = fmaxf(mx, __shfl_xor(mx, o));
    __shared__ float red[4];
    int wid = tid >> 6;
    if ((tid & 63) == 0) red[wid] = mx;
    __syncthreads();
    mx = fmaxf(fmaxf(red[0], red[1]), fmaxf(red[2], red[3]));
    __syncthreads();

    float sum = 0.0f;
#pragma unroll
    for (int k = 0; k < 16; k++) {
        vals[k] = __expf(vals[k] - mx);
        sum += vals[k];
    }
#pragma unroll
    for (int o = 32; o > 0; o >>= 1) sum += __shfl_xor(sum, o);
    if ((tid & 63) == 0) red[wid] = sum;
    __syncthreads();
    sum = red[0] + red[1] + red[2] + red[3];
    __syncthreads();
    float inv = 1.0f / sum;

    float qs = 0.0f;
#pragma unroll
    for (int k = 0; k < 16; k++) {
        __half h = __float2half_rn(vals[k] * inv);
        dst[tid + (k << 8)] = __half_as_ushort(h);
        qs += __half2float(h);
    }
#pragma unroll
    for (int o = 32; o > 0; o >>= 1) qs += __shfl_xor(qs, o);
    if ((tid & 63) == 0) red[wid] = qs;
    __syncthreads();
    if (tid == 0) {
        float q = red[0] + red[1] + red[2] + red[3];
        rowc[(size_t)s * N + i] = 1.0f / q;
    }
}

// ---------- softmax over O rows (4 wide) -> fp32 OW slots 0,1 ----------
__global__ __launch_bounds__(256) void softmax_O_kernel(const float* __restrict__ O,
                                                        float* __restrict__ OW) {
    int r = blockIdx.x * 256 + threadIdx.x;        // 0..8191 == i*2 + s
    if (r < 2 * N) {
        float4 x = *(const float4*)(O + (size_t)r * 4);
        float mx = fmaxf(fmaxf(x.x, x.y), fmaxf(x.z, x.w));
        float e0 = __expf(x.x - mx), e1 = __expf(x.y - mx);
        float e2 = __expf(x.z - mx), e3 = __expf(x.w - mx);
        float inv = 1.0f / (e0 + e1 + e2 + e3);
        int i = r >> 1, s = r & 1;
        *(float4*)(OW + (size_t)s * SLOT + (size_t)i * 4) =
            make_float4(e0 * inv, e1 * inv, e2 * inv, e3 * inv);
    }
}

// ---------- MFMA GEMM: C[pair] = A[pair>>ash] x B[pair&bmask], fp16 in/out ----------
// (validated in R10) grid = npairs*1024 blocks; 128x128 C-tile; 4 waves x 64x64.
__global__ __launch_bounds__(256) void gemm_kernel(const unsigned short* __restrict__ Abase,
                                                   const unsigned short* __restrict__ Bbase,
                                                   unsigned short* __restrict__ Cbase,
                                                   int ash, int bmask) {
    int bid = blockIdx.x;
    int pair = bid >> 10;
    int tile = bid & 1023;
    int i0 = (tile >> 5) << 7;
    int j0 = (tile & 31) << 7;
    const unsigned short* A = Abase + (size_t)(pair >> ash) * NN;
    const unsigned short* B = Bbase + (size_t)(pair & bmask) * NN;
    unsigned short* Pm = Cbase + (size_t)pair * NN;

    __shared__ _Float16 Asd[128][40];
    __shared__ unsigned int Btw[128][20];

    const int tid = threadIdx.x;
    const int w = tid >> 6, ln = tid & 63;
    const int wrow = (w >> 1) << 6, wcol = (w & 1) << 6;
    const int q = ln >> 4, l15 = ln & 15;

    const int ar = tid >> 1, ah = tid & 1;
    const int bk2 = tid & 15, bng = tid >> 4;

    f32x4 acc[4][4] = {};

    for (int k0 = 0; k0 < N; k0 += 32) {
        const uint4* ga = (const uint4*)(A + (size_t)(i0 + ar) * N + k0 + ah * 16);
        uint4 a0 = ga[0], a1 = ga[1];
        *(uint4*)&Asd[ar][ah * 16] = a0;
        *(uint4*)&Asd[ar][ah * 16 + 8] = a1;
        const unsigned short* gb0 = B + (size_t)(k0 + 2 * bk2) * N + j0 + bng * 8;
        uint4 b0 = *(const uint4*)gb0;
        uint4 b1 = *(const uint4*)(gb0 + N);
        const unsigned short* e0 = (const unsigned short*)&b0;
        const unsigned short* e1 = (const unsigned short*)&b1;
#pragma unroll
        for (int jj = 0; jj < 8; jj++)
            Btw[bng * 8 + jj][bk2] = (unsigned)e0[jj] | ((unsigned)e1[jj] << 16);
        __syncthreads();

        f16x8 af[4], bf[4];
#pragma unroll
        for (int ti = 0; ti < 4; ti++)
            af[ti] = *(const f16x8*)&Asd[wrow + ti * 16 + l15][q * 8];
#pragma unroll
        for (int tj = 0; tj < 4; tj++)
            bf[tj] = *(const f16x8*)&Btw[wcol + tj * 16 + l15][q * 4];
#pragma unroll
        for (int ti = 0; ti < 4; ti++)
#pragma unroll
            for (int tj = 0; tj < 4; tj++)
                acc[ti][tj] = __builtin_amdgcn_mfma_f32_16x16x32_f16(
                    af[ti], bf[tj], acc[ti][tj], 0, 0, 0);
        __syncthreads();
    }

#pragma unroll
    for (int ti = 0; ti < 4; ti++)
#pragma unroll
        for (int tj = 0; tj < 4; tj++)
#pragma unroll
            for (int reg = 0; reg < 4; reg++) {
                int row = i0 + wrow + ti * 16 + q * 4 + reg;
                int col = j0 + wcol + tj * 16 + l15;
                Pm[(size_t)row * N + col] =
                    __half_as_ushort(__float2half_rn(acc[ti][tj][reg]));
            }
}

// ---------- row sums of fp16 matrices -> rc = 1/sum (exact stochasticity) ----------
__global__ __launch_bounds__(256) void rowsum_kernel(const unsigned short* __restrict__ P,
                                                     float* __restrict__ rc) {
    int b = blockIdx.x;                        // mat*4096 + row
    const unsigned short* row = P + (size_t)b * N;
    int tid = threadIdx.x;
    const uint4* rp = (const uint4*)row + tid * 2;
    uint4 w0 = rp[0], w1 = rp[1];
    const __half* h0 = (const __half*)&w0;
    const __half* h1 = (const __half*)&w1;
    float s = 0.0f;
#pragma unroll
    for (int j = 0; j < 8; j++) s += __half2float(h0[j]) + __half2float(h1[j]);
#pragma unroll
    for (int o = 32; o > 0; o >>= 1) s += __shfl_xor(s, o);
    __shared__ float red[4];
    if ((tid & 63) == 0) red[tid >> 6] = s;
    __syncthreads();
    if (tid == 0) rc[b] = 1.0f / (red[0] + red[1] + red[2] + red[3]);
}

// ---------- generic N x 4 projection: dst[i][c] = rc[i] * sum_j M[i][j]*Q[j][c] ----------
__global__ __launch_bounds__(256) void proj_kernel(const unsigned short* __restrict__ Tm,
                                                   const unsigned short* __restrict__ P,
                                                   const float* __restrict__ rowc,
                                                   const float* __restrict__ rowc2,
                                                   float* __restrict__ OW, int phase) {
    int bid = blockIdx.x;
    int s = bid >> 12, i = bid & 4095;
    const unsigned short* M; const float* rc; const float* Q; float* dst;
    if (phase == 1) {
        if (s < 4) { M = Tm + (size_t)(s >> 1) * NN; rc = rowc + (size_t)(s >> 1) * N;
                     Q = OW + (size_t)(s & 1) * SLOT; dst = OW + (size_t)(2 + s) * SLOT; }
        else { int q = s - 4; M = P + (size_t)(q >> 1) * NN; rc = rowc2 + (size_t)(q >> 1) * N;
               Q = OW + (size_t)(q & 1) * SLOT; dst = OW + (size_t)(6 + q) * SLOT; }
    } else {
        int q = s; M = P + (size_t)(q >> 2) * NN; rc = rowc2 + (size_t)(q >> 2) * N;
        Q = OW + (size_t)(2 + (q & 3)) * SLOT; dst = OW + (size_t)(14 + q) * SLOT;
    }
    const unsigned short* row = M + (size_t)i * N;
    int tid = threadIdx.x;
    const uint4* rp = (const uint4*)row + tid * 2;
    uint4 w0 = rp[0], w1 = rp[1];
    const __half* h0 = (const __half*)&w0;
    const __half* h1 = (const __half*)&w1;
    int j0 = tid * 16;
    float ac[4] = {};
#pragma unroll
    for (int j = 0; j < 8; j++) {
        float tv = __half2float(h0[j]);
        float4 o = *(const float4*)(Q + (size_t)(j0 + j) * 4);
        ac[0] += tv * o.x; ac[1] += tv * o.y; ac[2] += tv * o.z; ac[3] += tv * o.w;
        float tv1 = __half2float(h1[j]);
        float4 o1 = *(const float4*)(Q + (size_t)(j0 + 8 + j) * 4);
        ac[0] += tv1 * o1.x; ac[1] += tv1 * o1.y; ac[2] += tv1 * o1.z; ac[3] += tv1 * o1.w;
    }
#pragma unroll
    for (int e = 0; e < 4; e++)
#pragma unroll
        for (int o = 32; o > 0; o >>= 1) ac[e] += __shfl_xor(ac[e], o);
    __shared__ float red[4][4];
    if ((tid & 63) == 0)
#pragma unroll
        for (int e = 0; e < 4; e++) red[tid >> 6][e] = ac[e];
    __syncthreads();
    if (tid < 4)
        dst[(size_t)i * 4 + tid] =
            (red[0][tid] + red[1][tid] + red[2][tid] + red[3][tid]) * rc[i];
}

// ---------- async tile staging: next step's 64 KiB matrix tile -> LDS ----------
// global_load_lds width=16: zero VGPR footprint, no waitcnt at issue (the fix
// for R11's AGPR-spill drain). Per wave: 16 instrs x 1 KiB. LDS layout is
// linear mt[row][col]; lane ln covers (row0 + ln>>4, granule ln&15), which is
// exactly lds_base + ln*16 — contiguous as required by the instruction.
__device__ __forceinline__ void stage_tile(const unsigned short* __restrict__ M,
                                           unsigned short* mt0,
                                           size_t goff, int w4) {
#pragma unroll
    for (int t = 0; t < 16; t++) {
        const int row0 = w4 * 64 + t * 4;
        __builtin_amdgcn_global_load_lds(
            (const __attribute__((address_space(1))) unsigned int*)(M + goff + (size_t)row0 * N),
            (__attribute__((address_space(3))) unsigned int*)(mt0 + row0 * CPB),
            16, 0, 0);
    }
}

// ---------- persistent scan (regular launch, p2p sync; NPART=16 tiling) ----------
// 512 blocks: jb = bid&31 (128 cols), ic = bid>>5 (256 rows).
// wait ready[ic] >= 32k; bump ready[jb>>1]. Triple-buffered partials.
// Block jb<OPS computes output projection jb via OW slot (m,jb)-indexed.
//
// R12: tile prefetch via global_load_lds into mt[256][128] (64 KiB LDS).
// Issue point: after the publish-drain __syncthreads, before the bump —
// loads fly through bump/poll/stage; the stage barrier drains them right
// before the matvec consumes mt via ds_read_b128 (16-lane phases read
// contiguous 256 B rows -> 2-way bank aliasing, free). midx[k+2] and
// rc[mnext] prefetches also moved into the overlap window.
__global__ __launch_bounds__(256, 2) void scan_kernel(const unsigned short* __restrict__ Mbase,
                                                      const float* __restrict__ rc,
                                                      const float* __restrict__ OW,
                                                      const unsigned char* __restrict__ midx,
                                                      float* __restrict__ vwpart,
                                                      unsigned* __restrict__ ready,
                                                      float* __restrict__ out,
                                                      int S, int OPS) {
    const int tid = threadIdx.x;
    const int jb = blockIdx.x & 31;
    const int ic = blockIdx.x >> 5;      // 0..15
    const int i0 = ic * RPB;
    const int j0 = jb * CPB;

    __shared__ unsigned short mt[RPB][CPB];   // 64 KiB staged matrix tile
    __shared__ float v[RPB];      // raw state rows
    __shared__ float vc[RPB];     // row-mass-corrected state rows
    __shared__ float colacc[CPB];
    __shared__ float oacc[4];

    const int cg = tid & 15;             // col group: 8 cols each
    const int rg = tid >> 4;             // row group: 16 groups x 16 rows

    const int w4 = tid >> 6;             // wave id
    const int ln = tid & 63;
    // per-lane global offset within a tile: row (ln>>4), granule (ln&15)
    const size_t goff = (size_t)(i0 + (ln >> 4)) * N + j0 + (ln & 15) * 8;

    unsigned* wait_ctr = &ready[ic * 64];
    unsigned* bump_ctr = &ready[(jb >> 1) * 64];

    // ---- software pipeline: m / rc-row one step ahead ----
    int mcur = (int)midx[0];
    int mnxt = (S > 1) ? (int)midx[1] : 0;
    float rc_cur = rc[(size_t)mcur * N + i0 + tid];
    float rc_nxt = (S > 1) ? rc[(size_t)mnxt * N + i0 + tid] : 0.0f;
    stage_tile(Mbase + (size_t)mcur * NN, &mt[0][0], goff, w4);   // tile for step 0

    for (int k = 0; k < S; k++) {
        const int m = mcur;
        const float* vin  = vwpart + (size_t)(k % 3) * (NPART * N);
        float*       vout = vwpart + (size_t)((k + 1) % 3) * (NPART * N);

        // ---- wait for this step's input partials (monotone counter) ----
        if (tid == 0) {
            unsigned target = 32u * (unsigned)k;
            while (AL(wait_ctr) < target) __builtin_amdgcn_s_sleep(1);
        }
        // RAW barrier: control-only sync; must NOT drain vmcnt — the tile
        // loads (issued last iteration) are still in flight here.
        asm volatile("" ::: "memory");
        __builtin_amdgcn_s_barrier();
        asm volatile("" ::: "memory");

        // ---- stage v rows: all 256 threads sum 16 partials for one row ----
        {
            float accv = 0.0f;
#pragma unroll
            for (int p = 0; p < NPART; p++) accv += AL(&vin[p * N + i0 + tid]);
            v[tid] = accv;
            vc[tid] = accv * rc_cur;
        }
        if (tid < CPB) colacc[tid] = 0.0f;
        if (tid < 4) oacc[tid] = 0.0f;
        __syncthreads();   // drains vmcnt(0): stage values AND tile loads -> mt valid

        // ---- partial matvec from LDS tile: rows [rg*16,+16), granule cg ----
        float a[8];
#pragma unroll
        for (int e = 0; e < 8; e++) a[e] = 0.0f;
#pragma unroll
        for (int r = 0; r < 16; r++) {
            uint4 w = *(const uint4*)&mt[rg * 16 + r][cg * 8];
            float vi = vc[rg * 16 + r];
            float2 f0 = __half22float2(*(__half2*)&w.x);
            float2 f1 = __half22float2(*(__half2*)&w.y);
            float2 f2 = __half22float2(*(__half2*)&w.z);
            float2 f3 = __half22float2(*(__half2*)&w.w);
            a[0] += vi * f0.x; a[1] += vi * f0.y;
            a[2] += vi * f1.x; a[3] += vi * f1.y;
            a[4] += vi * f2.x; a[5] += vi * f2.y;
            a[6] += vi * f3.x; a[7] += vi * f3.y;
        }
#pragma unroll
        for (int e = 0; e < 8; e++) atomicAdd(&colacc[cg * 8 + e], a[e]);

        // ---- output projection jb (blocks jb < OPS) — RAW state v ----
        if (jb < OPS) {
            int slot;
            if (OPS == 4) slot = (jb == 0) ? (m >> 3) : (jb == 1) ? 2 + (m >> 2)
                               : (jb == 2) ? 6 + (m >> 1) : 14 + m;
            else if (OPS == 2) slot = (jb == 0) ? (m >> 1) : 2 + m;
            else slot = m;
            const float* pr = OW + (size_t)slot * SLOT;
            int r = tid >> 2, c = tid & 3;   // r in [0,64)
            float p = v[r]       * pr[(size_t)(i0 + r) * 4 + c]
                    + v[r + 64]  * pr[(size_t)(i0 + r + 64) * 4 + c]
                    + v[r + 128] * pr[(size_t)(i0 + r + 128) * 4 + c]
                    + v[r + 192] * pr[(size_t)(i0 + r + 192) * 4 + c];
            p += __shfl_down(p, 32); p += __shfl_down(p, 16);
            p += __shfl_down(p, 8);  p += __shfl_down(p, 4);
            if ((tid & 63) < 4) atomicAdd(&oacc[c], p);
        }
        __syncthreads();   // A: mt fully consumed, colacc complete

        // ---- publish this block's exclusive partial slice (agent-scope) ----
        if (tid < CPB) AS(&vout[(size_t)ic * N + j0 + tid], colacc[tid]);
        if (jb < OPS && tid < 4) atomicAdd(&out[(k * OPS + jb) * 4 + tid], oacc[tid]);
        __syncthreads();   // B: drains vmcnt(0) -> slice visible at MALL
                           // (tile loads not yet issued, so this drain is cheap)

        // ---- overlap window: issue next tile + next-next descriptor loads ----
        if (k + 1 < S) {
            stage_tile(Mbase + (size_t)mnxt * NN, &mt[0][0], goff, w4);   // async
        }
        if (tid == 0) {
            __hip_atomic_fetch_add(bump_ctr, 1u, __ATOMIC_RELAXED,
                                   __HIP_MEMORY_SCOPE_AGENT);
        }
        mcur = mnxt; rc_cur = rc_nxt;
        if (k + 2 < S) {
            mnxt = (int)midx[k + 2];
            rc_nxt = rc[(size_t)mnxt * N + i0 + tid];
        }
    }
}

extern "C" void kernel_launch(void* const* d_in, const int* in_sizes, int n_in,
                              void* d_out, int out_size, void* d_ws, size_t ws_size,
                              hipStream_t stream) {
    const float* sd  = (const float*)d_in[0];   // [4096]
    const int*   seq = (const int*)d_in[1];     // [4096]
    const float* T   = (const float*)d_in[2];   // [4096,2,4096]
    const float* O   = (const float*)d_in[3];   // [4096,2,4]
    float* out = (float*)d_out;                 // [4096,4]

    const size_t TM_SZ = 2 * NN * 2;            // 64 MiB
    const size_t P_SZ  = 4 * NN * 2;            // 128 MiB
    const size_t P4_SZ = 16 * NN * 2;           // 512 MiB
    const size_t AUX_SZ = 0x400000;             // 4 MiB aux block

    int mode = (ws_size >= TM_SZ + P_SZ + P4_SZ + AUX_SZ) ? 2
             : (ws_size >= TM_SZ + P_SZ + AUX_SZ) ? 1 : 0;

    char* ws = (char*)d_ws;
    unsigned short* Tm = (unsigned short*)ws;
    unsigned short* P  = (unsigned short*)(ws + TM_SZ);
    unsigned short* P4 = (unsigned short*)(ws + TM_SZ + P_SZ);
    char* aux = ws + (mode == 2 ? TM_SZ + P_SZ + P4_SZ
                    : mode == 1 ? TM_SZ + P_SZ : TM_SZ);
    float* rowc   = (float*)(aux);               // 32 KB
    float* rowc2  = (float*)(aux + 0x8000);      // 64 KB
    float* rowc4  = (float*)(aux + 0x18000);     // 256 KB
    float* OW     = (float*)(aux + 0x58000);     // 32 slots x 64 KB = 2 MB
    float* vwpart = (float*)(aux + 0x258000);    // 768 KB
    unsigned* ready = (unsigned*)(aux + 0x318000);
    unsigned char* midx = (unsigned char*)(aux + 0x319000);

    hipLaunchKernelGGL(init_kernel, dim3(1536), dim3(256), 0, stream, sd, vwpart, ready, out);
    hipLaunchKernelGGL(build_desc_kernel, dim3(1), dim3(256), 0, stream, seq, midx, mode);
    hipLaunchKernelGGL(softmax_T_kernel, dim3(2 * N), dim3(256), 0, stream, T, Tm, rowc);
    hipLaunchKernelGGL(softmax_O_kernel, dim3(32), dim3(256), 0, stream, O, OW);

    if (mode == 2) {
        hipLaunchKernelGGL(gemm_kernel, dim3(4 * 1024), dim3(256), 0, stream, Tm, Tm, P, 1, 1);
        hipLaunchKernelGGL(rowsum_kernel, dim3(4 * N), dim3(256), 0, stream, P, rowc2);
        hipLaunchKernelGGL(gemm_kernel, dim3(16 * 1024), dim3(256), 0, stream, P, P, P4, 2, 3);
        hipLaunchKernelGGL(rowsum_kernel, dim3(16 * N), dim3(256), 0, stream, P4, rowc4);
        hipLaunchKernelGGL(proj_kernel, dim3(12 * N), dim3(256), 0, stream, Tm, P, rowc, rowc2, OW, 1);
        hipLaunchKernelGGL(proj_kernel, dim3(16 * N), dim3(256), 0, stream, Tm, P, rowc, rowc2, OW, 2);
        hipLaunchKernelGGL(scan_kernel, dim3(512), dim3(256), 0, stream,
                           P4, rowc4, OW, midx, vwpart, ready, out, L / 4, 4);
    } else if (mode == 1) {
        hipLaunchKernelGGL(gemm_kernel, dim3(4 * 1024), dim3(256), 0, stream, Tm, Tm, P, 1, 1);
        hipLaunchKernelGGL(rowsum_kernel, dim3(4 * N), dim3(256), 0, stream, P, rowc2);
        hipLaunchKernelGGL(proj_kernel, dim3(4 * N), dim3(256), 0, stream, Tm, P, rowc, rowc2, OW, 1);
        hipLaunchKernelGGL(scan_kernel, dim3(512), dim3(256), 0, stream,
                           P, rowc2, OW, midx, vwpart, ready, out, L / 2, 2);
    } else {
        hipLaunchKernelGGL(scan_kernel, dim3(512), dim3(256), 0, stream,
                           Tm, rowc, OW, midx, vwpart, ready, out, L, 1);
    }
}

// Round 4
// 20178.418 us; speedup vs baseline: 1.2472x; 1.1175x over previous
//
#include <hip/hip_runtime.h>
#include <hip/hip_fp16.h>

#define N 4096
#define L 4096
#define NPART 16   // i-chunks (rows 256 each)
#define NJB 32     // j-blocks (cols 128 each)
#define CPB 128    // cols per block
#define RPB 256    // rows per block

#define NN ((size_t)N * (size_t)N)
#define SLOT ((size_t)N * 4)

#define AS(p, v) __hip_atomic_store((p), (v), __ATOMIC_RELAXED, __HIP_MEMORY_SCOPE_AGENT)
#define AL(p)    __hip_atomic_load((p), __ATOMIC_RELAXED, __HIP_MEMORY_SCOPE_AGENT)

typedef _Float16 f16x8 __attribute__((ext_vector_type(8)));
typedef float f32x4 __attribute__((ext_vector_type(4)));

// ---------- init: zero d_out, seed triple partial buffer, zero ready flags ----------
__global__ __launch_bounds__(256) void init_kernel(const float* __restrict__ sd,
                                                   float* __restrict__ vwpart,
                                                   unsigned* __restrict__ ready,
                                                   float* __restrict__ out) {
    int g = blockIdx.x * 256 + threadIdx.x;          // grid 1536 -> 393216 threads
    if (g < L * 4) out[g] = 0.0f;
    if (g < 3 * NPART * N) AS(&vwpart[g], (g < N) ? sd[g] : 0.0f);  // buf0 part0 = sd
    if (g < NPART * 64) AS(&ready[g], 0u);
}

// ---------- descriptor build: robust int32/int64 decode; mode 0/1/2 = direct/pair/quad ----------
__global__ __launch_bounds__(256) void build_desc_kernel(const int* __restrict__ seq32,
                                                         unsigned char* __restrict__ midx,
                                                         int mode) {
    __shared__ int any_odd;
    if (threadIdx.x == 0) any_odd = 0;
    __syncthreads();
    int acc = 0;
    for (int i = threadIdx.x; i < L / 2; i += 256) acc |= seq32[2 * i + 1];
    if (acc) any_odd = 1;
    __syncthreads();
    const int is64 = (any_odd == 0);
#define SYM(t) ((is64 ? seq32[2 * (t)] : seq32[(t)]) & 1)
    if (mode == 2) {
        for (int k = threadIdx.x; k < L / 4; k += 256)
            midx[k] = (unsigned char)(SYM(4 * k) * 8 + SYM(4 * k + 1) * 4 +
                                      SYM(4 * k + 2) * 2 + SYM(4 * k + 3));
    } else if (mode == 1) {
        for (int k = threadIdx.x; k < L / 2; k += 256)
            midx[k] = (unsigned char)(SYM(2 * k) * 2 + SYM(2 * k + 1));
    } else {
        for (int t = threadIdx.x; t < L; t += 256)
            midx[t] = (unsigned char)SYM(t);
    }
#undef SYM
}

// ---------- softmax over T rows -> fp16 Tm[s][i][j] + row-mass correction ----------
__global__ __launch_bounds__(256) void softmax_T_kernel(const float* __restrict__ T,
                                                        unsigned short* __restrict__ Tm,
                                                        float* __restrict__ rowc) {
    int row = blockIdx.x;              // 0..8191 == i*2 + s
    int i = row >> 1, s = row & 1;
    const float* src = T + (size_t)row * N;
    unsigned short* dst = Tm + ((size_t)s << 24) + ((size_t)i << 12);
    int tid = threadIdx.x;

    float vals[16];
    float mx = -1e30f;
#pragma unroll
    for (int k = 0; k < 16; k++) {
        vals[k] = src[tid + (k << 8)];
        mx = fmaxf(mx, vals[k]);
    }
#pragma unroll
    for (int o = 32; o > 0; o >>= 1) mx = fmaxf(mx, __shfl_xor(mx, o));
    __shared__ float red[4];
    int wid = tid >> 6;
    if ((tid & 63) == 0) red[wid] = mx;
    __syncthreads();
    mx = fmaxf(fmaxf(red[0], red[1]), fmaxf(red[2], red[3]));
    __syncthreads();

    float sum = 0.0f;
#pragma unroll
    for (int k = 0; k < 16; k++) {
        vals[k] = __expf(vals[k] - mx);
        sum += vals[k];
    }
#pragma unroll
    for (int o = 32; o > 0; o >>= 1) sum += __shfl_xor(sum, o);
    if ((tid & 63) == 0) red[wid] = sum;
    __syncthreads();
    sum = red[0] + red[1] + red[2] + red[3];
    __syncthreads();
    float inv = 1.0f / sum;

    float qs = 0.0f;
#pragma unroll
    for (int k = 0; k < 16; k++) {
        __half h = __float2half_rn(vals[k] * inv);
        dst[tid + (k << 8)] = __half_as_ushort(h);
        qs += __half2float(h);
    }
#pragma unroll
    for (int o = 32; o > 0; o >>= 1) qs += __shfl_xor(qs, o);
    if ((tid & 63) == 0) red[wid] = qs;
    __syncthreads();
    if (tid == 0) {
        float q = red[0] + red[1] + red[2] + red[3];
        rowc[(size_t)s * N + i] = 1.0f / q;
    }
}

// ---------- softmax over O rows (4 wide) -> fp32 OW slots 0,1 ----------
__global__ __launch_bounds__(256) void softmax_O_kernel(const float* __restrict__ O,
                                                        float* __restrict__ OW) {
    int r = blockIdx.x * 256 + threadIdx.x;        // 0..8191 == i*2 + s
    if (r < 2 * N) {
        float4 x = *(const float4*)(O + (size_t)r * 4);
        float mx = fmaxf(fmaxf(x.x, x.y), fmaxf(x.z, x.w));
        float e0 = __expf(x.x - mx), e1 = __expf(x.y - mx);
        float e2 = __expf(x.z - mx), e3 = __expf(x.w - mx);
        float inv = 1.0f / (e0 + e1 + e2 + e3);
        int i = r >> 1, s = r & 1;
        *(float4*)(OW + (size_t)s * SLOT + (size_t)i * 4) =
            make_float4(e0 * inv, e1 * inv, e2 * inv, e3 * inv);
    }
}

// ---------- MFMA GEMM: C[pair] = A[pair>>ash] x B[pair&bmask], fp16 in/out ----------
// (validated in R10) grid = npairs*1024 blocks; 128x128 C-tile; 4 waves x 64x64.
__global__ __launch_bounds__(256) void gemm_kernel(const unsigned short* __restrict__ Abase,
                                                   const unsigned short* __restrict__ Bbase,
                                                   unsigned short* __restrict__ Cbase,
                                                   int ash, int bmask) {
    int bid = blockIdx.x;
    int pair = bid >> 10;
    int tile = bid & 1023;
    int i0 = (tile >> 5) << 7;
    int j0 = (tile & 31) << 7;
    const unsigned short* A = Abase + (size_t)(pair >> ash) * NN;
    const unsigned short* B = Bbase + (size_t)(pair & bmask) * NN;
    unsigned short* Pm = Cbase + (size_t)pair * NN;

    __shared__ _Float16 Asd[128][40];
    __shared__ unsigned int Btw[128][20];

    const int tid = threadIdx.x;
    const int w = tid >> 6, ln = tid & 63;
    const int wrow = (w >> 1) << 6, wcol = (w & 1) << 6;
    const int q = ln >> 4, l15 = ln & 15;

    const int ar = tid >> 1, ah = tid & 1;
    const int bk2 = tid & 15, bng = tid >> 4;

    f32x4 acc[4][4] = {};

    for (int k0 = 0; k0 < N; k0 += 32) {
        const uint4* ga = (const uint4*)(A + (size_t)(i0 + ar) * N + k0 + ah * 16);
        uint4 a0 = ga[0], a1 = ga[1];
        *(uint4*)&Asd[ar][ah * 16] = a0;
        *(uint4*)&Asd[ar][ah * 16 + 8] = a1;
        const unsigned short* gb0 = B + (size_t)(k0 + 2 * bk2) * N + j0 + bng * 8;
        uint4 b0 = *(const uint4*)gb0;
        uint4 b1 = *(const uint4*)(gb0 + N);
        const unsigned short* e0 = (const unsigned short*)&b0;
        const unsigned short* e1 = (const unsigned short*)&b1;
#pragma unroll
        for (int jj = 0; jj < 8; jj++)
            Btw[bng * 8 + jj][bk2] = (unsigned)e0[jj] | ((unsigned)e1[jj] << 16);
        __syncthreads();

        f16x8 af[4], bf[4];
#pragma unroll
        for (int ti = 0; ti < 4; ti++)
            af[ti] = *(const f16x8*)&Asd[wrow + ti * 16 + l15][q * 8];
#pragma unroll
        for (int tj = 0; tj < 4; tj++)
            bf[tj] = *(const f16x8*)&Btw[wcol + tj * 16 + l15][q * 4];
#pragma unroll
        for (int ti = 0; ti < 4; ti++)
#pragma unroll
            for (int tj = 0; tj < 4; tj++)
                acc[ti][tj] = __builtin_amdgcn_mfma_f32_16x16x32_f16(
                    af[ti], bf[tj], acc[ti][tj], 0, 0, 0);
        __syncthreads();
    }

#pragma unroll
    for (int ti = 0; ti < 4; ti++)
#pragma unroll
        for (int tj = 0; tj < 4; tj++)
#pragma unroll
            for (int reg = 0; reg < 4; reg++) {
                int row = i0 + wrow + ti * 16 + q * 4 + reg;
                int col = j0 + wcol + tj * 16 + l15;
                Pm[(size_t)row * N + col] =
                    __half_as_ushort(__float2half_rn(acc[ti][tj][reg]));
            }
}

// ---------- row sums of fp16 matrices -> rc = 1/sum (exact stochasticity) ----------
__global__ __launch_bounds__(256) void rowsum_kernel(const unsigned short* __restrict__ P,
                                                     float* __restrict__ rc) {
    int b = blockIdx.x;                        // mat*4096 + row
    const unsigned short* row = P + (size_t)b * N;
    int tid = threadIdx.x;
    const uint4* rp = (const uint4*)row + tid * 2;
    uint4 w0 = rp[0], w1 = rp[1];
    const __half* h0 = (const __half*)&w0;
    const __half* h1 = (const __half*)&w1;
    float s = 0.0f;
#pragma unroll
    for (int j = 0; j < 8; j++) s += __half2float(h0[j]) + __half2float(h1[j]);
#pragma unroll
    for (int o = 32; o > 0; o >>= 1) s += __shfl_xor(s, o);
    __shared__ float red[4];
    if ((tid & 63) == 0) red[tid >> 6] = s;
    __syncthreads();
    if (tid == 0) rc[b] = 1.0f / (red[0] + red[1] + red[2] + red[3]);
}

// ---------- generic N x 4 projection: dst[i][c] = rc[i] * sum_j M[i][j]*Q[j][c] ----------
__global__ __launch_bounds__(256) void proj_kernel(const unsigned short* __restrict__ Tm,
                                                   const unsigned short* __restrict__ P,
                                                   const float* __restrict__ rowc,
                                                   const float* __restrict__ rowc2,
                                                   float* __restrict__ OW, int phase) {
    int bid = blockIdx.x;
    int s = bid >> 12, i = bid & 4095;
    const unsigned short* M; const float* rc; const float* Q; float* dst;
    if (phase == 1) {
        if (s < 4) { M = Tm + (size_t)(s >> 1) * NN; rc = rowc + (size_t)(s >> 1) * N;
                     Q = OW + (size_t)(s & 1) * SLOT; dst = OW + (size_t)(2 + s) * SLOT; }
        else { int q = s - 4; M = P + (size_t)(q >> 1) * NN; rc = rowc2 + (size_t)(q >> 1) * N;
               Q = OW + (size_t)(q & 1) * SLOT; dst = OW + (size_t)(6 + q) * SLOT; }
    } else {
        int q = s; M = P + (size_t)(q >> 2) * NN; rc = rowc2 + (size_t)(q >> 2) * N;
        Q = OW + (size_t)(2 + (q & 3)) * SLOT; dst = OW + (size_t)(14 + q) * SLOT;
    }
    const unsigned short* row = M + (size_t)i * N;
    int tid = threadIdx.x;
    const uint4* rp = (const uint4*)row + tid * 2;
    uint4 w0 = rp[0], w1 = rp[1];
    const __half* h0 = (const __half*)&w0;
    const __half* h1 = (const __half*)&w1;
    int j0 = tid * 16;
    float ac[4] = {};
#pragma unroll
    for (int j = 0; j < 8; j++) {
        float tv = __half2float(h0[j]);
        float4 o = *(const float4*)(Q + (size_t)(j0 + j) * 4);
        ac[0] += tv * o.x; ac[1] += tv * o.y; ac[2] += tv * o.z; ac[3] += tv * o.w;
        float tv1 = __half2float(h1[j]);
        float4 o1 = *(const float4*)(Q + (size_t)(j0 + 8 + j) * 4);
        ac[0] += tv1 * o1.x; ac[1] += tv1 * o1.y; ac[2] += tv1 * o1.z; ac[3] += tv1 * o1.w;
    }
#pragma unroll
    for (int e = 0; e < 4; e++)
#pragma unroll
        for (int o = 32; o > 0; o >>= 1) ac[e] += __shfl_xor(ac[e], o);
    __shared__ float red[4][4];
    if ((tid & 63) == 0)
#pragma unroll
        for (int e = 0; e < 4; e++) red[tid >> 6][e] = ac[e];
    __syncthreads();
    if (tid < 4)
        dst[(size_t)i * 4 + tid] =
            (red[0][tid] + red[1][tid] + red[2][tid] + red[3][tid]) * rc[i];
}

// ---------- async tile staging: next step's 64 KiB matrix tile -> LDS ----------
// global_load_lds width=16: zero VGPR footprint, no waitcnt at issue.
__device__ __forceinline__ void stage_tile(const unsigned short* __restrict__ M,
                                           unsigned short* mt0,
                                           size_t goff, int w4) {
#pragma unroll
    for (int t = 0; t < 16; t++) {
        const int row0 = w4 * 64 + t * 4;
        __builtin_amdgcn_global_load_lds(
            (const __attribute__((address_space(1))) unsigned int*)(M + goff + (size_t)row0 * N),
            (__attribute__((address_space(3))) unsigned int*)(mt0 + row0 * CPB),
            16, 0, 0);
    }
}

// ---------- persistent scan (regular launch, p2p sync; NPART=16 tiling) ----------
// 512 blocks: jb = bid&31 (128 cols), ic = bid>>5 (256 rows).
// R13 sync: per-producer FLAG STORES instead of a 32-way contended atomic
// counter. Producer (ic,jb) after its publish-drain stores k+1 into
// ready[(jb>>1)*64 + ic*2+(jb&1)] — 512 distinct addresses, zero RMW
// contention (the old counter serialized 32 cross-XCD RMWs per step at
// the MALL ≈ 10-16 µs — the dominant per-step cost per R12's null).
// Consumer at step k: 32 lanes poll the 32 flags (one coalesced 128 B
// line) until all >= k. Same monotone ordering semantics as the counter.
// R12's LDS tile prefetch (global_load_lds) retained unchanged.
__global__ __launch_bounds__(256, 2) void scan_kernel(const unsigned short* __restrict__ Mbase,
                                                      const float* __restrict__ rc,
                                                      const float* __restrict__ OW,
                                                      const unsigned char* __restrict__ midx,
                                                      float* __restrict__ vwpart,
                                                      unsigned* __restrict__ ready,
                                                      float* __restrict__ out,
                                                      int S, int OPS) {
    const int tid = threadIdx.x;
    const int jb = blockIdx.x & 31;
    const int ic = blockIdx.x >> 5;      // 0..15
    const int i0 = ic * RPB;
    const int j0 = jb * CPB;

    __shared__ unsigned short mt[RPB][CPB];   // 64 KiB staged matrix tile
    __shared__ float v[RPB];      // raw state rows
    __shared__ float vc[RPB];     // row-mass-corrected state rows
    __shared__ float colacc[CPB];
    __shared__ float oacc[4];

    const int cg = tid & 15;             // col group: 8 cols each
    const int rg = tid >> 4;             // row group: 16 groups x 16 rows

    const int w4 = tid >> 6;             // wave id
    const int ln = tid & 63;
    // per-lane global offset within a tile: row (ln>>4), granule (ln&15)
    const size_t goff = (size_t)(i0 + (ln >> 4)) * N + j0 + (ln & 15) * 8;

    unsigned* wait_flags = &ready[ic * 64];                       // 32 flags we poll
    unsigned* my_flag    = &ready[(jb >> 1) * 64 + ic * 2 + (jb & 1)];  // our slot

    // ---- software pipeline: m / rc-row one step ahead ----
    int mcur = (int)midx[0];
    int mnxt = (S > 1) ? (int)midx[1] : 0;
    float rc_cur = rc[(size_t)mcur * N + i0 + tid];
    float rc_nxt = (S > 1) ? rc[(size_t)mnxt * N + i0 + tid] : 0.0f;
    stage_tile(Mbase + (size_t)mcur * NN, &mt[0][0], goff, w4);   // tile for step 0

    for (int k = 0; k < S; k++) {
        const int m = mcur;
        const float* vin  = vwpart + (size_t)(k % 3) * (NPART * N);
        float*       vout = vwpart + (size_t)((k + 1) % 3) * (NPART * N);

        // ---- wait for this step's 32 input flags (no RMW anywhere) ----
        if (tid < 32) {
            while (AL(&wait_flags[tid]) < (unsigned)k) __builtin_amdgcn_s_sleep(1);
        }
        // RAW barrier: control-only sync; must NOT drain vmcnt — the tile
        // loads (issued last iteration) are still in flight here.
        asm volatile("" ::: "memory");
        __builtin_amdgcn_s_barrier();
        asm volatile("" ::: "memory");

        // ---- stage v rows: all 256 threads sum 16 partials for one row ----
        {
            float accv = 0.0f;
#pragma unroll
            for (int p = 0; p < NPART; p++) accv += AL(&vin[p * N + i0 + tid]);
            v[tid] = accv;
            vc[tid] = accv * rc_cur;
        }
        if (tid < CPB) colacc[tid] = 0.0f;
        if (tid < 4) oacc[tid] = 0.0f;
        __syncthreads();   // drains vmcnt(0): stage values AND tile loads -> mt valid

        // ---- partial matvec from LDS tile: rows [rg*16,+16), granule cg ----
        float a[8];
#pragma unroll
        for (int e = 0; e < 8; e++) a[e] = 0.0f;
#pragma unroll
        for (int r = 0; r < 16; r++) {
            uint4 w = *(const uint4*)&mt[rg * 16 + r][cg * 8];
            float vi = vc[rg * 16 + r];
            float2 f0 = __half22float2(*(__half2*)&w.x);
            float2 f1 = __half22float2(*(__half2*)&w.y);
            float2 f2 = __half22float2(*(__half2*)&w.z);
            float2 f3 = __half22float2(*(__half2*)&w.w);
            a[0] += vi * f0.x; a[1] += vi * f0.y;
            a[2] += vi * f1.x; a[3] += vi * f1.y;
            a[4] += vi * f2.x; a[5] += vi * f2.y;
            a[6] += vi * f3.x; a[7] += vi * f3.y;
        }
#pragma unroll
        for (int e = 0; e < 8; e++) atomicAdd(&colacc[cg * 8 + e], a[e]);

        // ---- output projection jb (blocks jb < OPS) — RAW state v ----
        if (jb < OPS) {
            int slot;
            if (OPS == 4) slot = (jb == 0) ? (m >> 3) : (jb == 1) ? 2 + (m >> 2)
                               : (jb == 2) ? 6 + (m >> 1) : 14 + m;
            else if (OPS == 2) slot = (jb == 0) ? (m >> 1) : 2 + m;
            else slot = m;
            const float* pr = OW + (size_t)slot * SLOT;
            int r = tid >> 2, c = tid & 3;   // r in [0,64)
            float p = v[r]       * pr[(size_t)(i0 + r) * 4 + c]
                    + v[r + 64]  * pr[(size_t)(i0 + r + 64) * 4 + c]
                    + v[r + 128] * pr[(size_t)(i0 + r + 128) * 4 + c]
                    + v[r + 192] * pr[(size_t)(i0 + r + 192) * 4 + c];
            p += __shfl_down(p, 32); p += __shfl_down(p, 16);
            p += __shfl_down(p, 8);  p += __shfl_down(p, 4);
            if ((tid & 63) < 4) atomicAdd(&oacc[c], p);
        }
        __syncthreads();   // A: mt fully consumed, colacc complete

        // ---- publish this block's exclusive partial slice (agent-scope) ----
        if (tid < CPB) AS(&vout[(size_t)ic * N + j0 + tid], colacc[tid]);
        if (jb < OPS && tid < 4) atomicAdd(&out[(k * OPS + jb) * 4 + tid], oacc[tid]);
        __syncthreads();   // B: drains vmcnt(0) -> slice visible at MALL

        // ---- flag first (visibility starts ASAP), then issue next tile ----
        if (tid == 0) AS(my_flag, (unsigned)(k + 1));
        if (k + 1 < S) {
            stage_tile(Mbase + (size_t)mnxt * NN, &mt[0][0], goff, w4);   // async
        }
        mcur = mnxt; rc_cur = rc_nxt;
        if (k + 2 < S) {
            mnxt = (int)midx[k + 2];
            rc_nxt = rc[(size_t)mnxt * N + i0 + tid];
        }
    }
}

extern "C" void kernel_launch(void* const* d_in, const int* in_sizes, int n_in,
                              void* d_out, int out_size, void* d_ws, size_t ws_size,
                              hipStream_t stream) {
    const float* sd  = (const float*)d_in[0];   // [4096]
    const int*   seq = (const int*)d_in[1];     // [4096]
    const float* T   = (const float*)d_in[2];   // [4096,2,4096]
    const float* O   = (const float*)d_in[3];   // [4096,2,4]
    float* out = (float*)d_out;                 // [4096,4]

    const size_t TM_SZ = 2 * NN * 2;            // 64 MiB
    const size_t P_SZ  = 4 * NN * 2;            // 128 MiB
    const size_t P4_SZ = 16 * NN * 2;           // 512 MiB
    const size_t AUX_SZ = 0x400000;             // 4 MiB aux block

    int mode = (ws_size >= TM_SZ + P_SZ + P4_SZ + AUX_SZ) ? 2
             : (ws_size >= TM_SZ + P_SZ + AUX_SZ) ? 1 : 0;

    char* ws = (char*)d_ws;
    unsigned short* Tm = (unsigned short*)ws;
    unsigned short* P  = (unsigned short*)(ws + TM_SZ);
    unsigned short* P4 = (unsigned short*)(ws + TM_SZ + P_SZ);
    char* aux = ws + (mode == 2 ? TM_SZ + P_SZ + P4_SZ
                    : mode == 1 ? TM_SZ + P_SZ : TM_SZ);
    float* rowc   = (float*)(aux);               // 32 KB
    float* rowc2  = (float*)(aux + 0x8000);      // 64 KB
    float* rowc4  = (float*)(aux + 0x18000);     // 256 KB
    float* OW     = (float*)(aux + 0x58000);     // 32 slots x 64 KB = 2 MB
    float* vwpart = (float*)(aux + 0x258000);    // 768 KB
    unsigned* ready = (unsigned*)(aux + 0x318000);
    unsigned char* midx = (unsigned char*)(aux + 0x319000);

    hipLaunchKernelGGL(init_kernel, dim3(1536), dim3(256), 0, stream, sd, vwpart, ready, out);
    hipLaunchKernelGGL(build_desc_kernel, dim3(1), dim3(256), 0, stream, seq, midx, mode);
    hipLaunchKernelGGL(softmax_T_kernel, dim3(2 * N), dim3(256), 0, stream, T, Tm, rowc);
    hipLaunchKernelGGL(softmax_O_kernel, dim3(32), dim3(256), 0, stream, O, OW);

    if (mode == 2) {
        hipLaunchKernelGGL(gemm_kernel, dim3(4 * 1024), dim3(256), 0, stream, Tm, Tm, P, 1, 1);
        hipLaunchKernelGGL(rowsum_kernel, dim3(4 * N), dim3(256), 0, stream, P, rowc2);
        hipLaunchKernelGGL(gemm_kernel, dim3(16 * 1024), dim3(256), 0, stream, P, P, P4, 2, 3);
        hipLaunchKernelGGL(rowsum_kernel, dim3(16 * N), dim3(256), 0, stream, P4, rowc4);
        hipLaunchKernelGGL(proj_kernel, dim3(12 * N), dim3(256), 0, stream, Tm, P, rowc, rowc2, OW, 1);
        hipLaunchKernelGGL(proj_kernel, dim3(16 * N), dim3(256), 0, stream, Tm, P, rowc, rowc2, OW, 2);
        hipLaunchKernelGGL(scan_kernel, dim3(512), dim3(256), 0, stream,
                           P4, rowc4, OW, midx, vwpart, ready, out, L / 4, 4);
    } else if (mode == 1) {
        hipLaunchKernelGGL(gemm_kernel, dim3(4 * 1024), dim3(256), 0, stream, Tm, Tm, P, 1, 1);
        hipLaunchKernelGGL(rowsum_kernel, dim3(4 * N), dim3(256), 0, stream, P, rowc2);
        hipLaunchKernelGGL(proj_kernel, dim3(4 * N), dim3(256), 0, stream, Tm, P, rowc, rowc2, OW, 1);
        hipLaunchKernelGGL(scan_kernel, dim3(512), dim3(256), 0, stream,
                           P, rowc2, OW, midx, vwpart, ready, out, L / 2, 2);
    } else {
        hipLaunchKernelGGL(scan_kernel, dim3(512), dim3(256), 0, stream,
                           Tm, rowc, OW, midx, vwpart, ready, out, L, 1);
    }
}